// Round 9
// baseline (117.620 us; speedup 1.0000x reference)
//
#include <hip/hip_runtime.h>

// Fake-quant (UniformAffineQuantizer): per-128-element-group asymmetric 4-bit
// fake quantization of an 8192x8192 f32 tensor. PASSED bit-exact in R8.
//
// NUMERICS (locked — do not change): the harness ref is the XLA-simplified
// chain (R8, absmax 0.0):
//   r  = max - min                      (group min/max, exact)
//   s  = clip(r * RN(1/15), 1e-5, 1e4)  [XLA: divide-by-broadcast-const ->
//                                        multiply by folded reciprocal]
//   zp = clip(-min / s, -1e4, 1e4)      [true IEEE f32 divide]
//   rzp= RNE(zp)
//   q  = RNE(x * RN(1/s))               [XLA: divide-by-broadcast [G,1] ->
//                                        mul by reciprocal(true divide, once)]
//   out= (clamp(q+rzp,0,15) - rzp) * s
//
// R9 perf change: 8 consecutive elems per lane (two float4 loads, 32B/lane)
// -> group = 16 lanes, 4-step __shfl_xor butterfly (was 5), 2x MLP, div
// chain amortized over 8 elems; nontemporal loads/stores (zero reuse).
// Min/max reduction order changes are exact -> still bit-identical.

using f32x4 = __attribute__((ext_vector_type(4))) float;

__global__ __launch_bounds__(256) void fakequant_g128_x2(
    const f32x4* __restrict__ x, f32x4* __restrict__ out, int npair)
{
    const float C15 = 1.0f / 15.0f;   // RN(1/15), constant-folded
    const int stride = gridDim.x * blockDim.x;

    for (int p = blockIdx.x * blockDim.x + threadIdx.x; p < npair; p += stride) {
        const int v = p * 2;          // this lane's two float4 slots
        f32x4 a = __builtin_nontemporal_load(&x[v]);
        f32x4 b = __builtin_nontemporal_load(&x[v + 1]);

        // local min/max over this lane's 8 consecutive elems (exact)
        float mn = fminf(fminf(fminf(a[0], a[1]), fminf(a[2], a[3])),
                         fminf(fminf(b[0], b[1]), fminf(b[2], b[3])));
        float mx = fmaxf(fmaxf(fmaxf(a[0], a[1]), fmaxf(a[2], a[3])),
                         fmaxf(fmaxf(b[0], b[1]), fmaxf(b[2], b[3])));

        // group = 16 consecutive lanes (16 lanes x 8 elems = 128)
        #pragma unroll
        for (int off = 8; off > 0; off >>= 1) {
            mn = fminf(mn, __shfl_xor(mn, off, 16));
            mx = fmaxf(mx, __shfl_xor(mx, off, 16));
        }

        // ---- locked numerics chain ----
        float s = (mx - mn) * C15;
        s = fminf(fmaxf(s, 1e-5f), 1e4f);
        float zp = (-mn) / s;                  // true IEEE divide
        zp = fminf(fmaxf(zp, -1e4f), 1e4f);
        float rzp = rintf(zp);
        float rs = 1.0f / s;                   // true IEEE divide, once

        f32x4 oa, ob;
        #pragma unroll
        for (int i = 0; i < 4; ++i)
            oa[i] = (fminf(fmaxf(rintf(a[i] * rs) + rzp, 0.0f), 15.0f) - rzp) * s;
        #pragma unroll
        for (int i = 0; i < 4; ++i)
            ob[i] = (fminf(fmaxf(rintf(b[i] * rs) + rzp, 0.0f), 15.0f) - rzp) * s;

        __builtin_nontemporal_store(oa, &out[v]);
        __builtin_nontemporal_store(ob, &out[v + 1]);
    }
}

extern "C" void kernel_launch(void* const* d_in, const int* in_sizes, int n_in,
                              void* d_out, int out_size, void* d_ws, size_t ws_size,
                              hipStream_t stream)
{
    const float* x = (const float*)d_in[0];
    float* o = (float*)d_out;

    const int n = in_sizes[0];          // 8192*8192 = 67108864
    const int npair = n / 8;            // 8388608 pairs of float4

    // 2048 blocks x 256 thr = 524288 threads, 16 iters each; the grid stride
    // (1048576 float4s) is a multiple of 32 -> 16-lane <-> 128-elem group
    // alignment preserved across iterations.
    const int block = 256;
    const int grid = 2048;

    fakequant_g128_x2<<<grid, block, 0, stream>>>(
        (const f32x4*)x, (f32x4*)o, npair);
}

// Round 10
// 113.850 us; speedup vs baseline: 1.0331x; 1.0331x over previous
//
#include <hip/hip_runtime.h>

// Fake-quant (UniformAffineQuantizer): per-128-element-group asymmetric 4-bit
// fake quantization of an 8192x8192 f32 tensor. Bit-exact since R8.
//
// NUMERICS (locked — do not change; R8 absmax 0.0): the harness ref is the
// XLA-simplified chain:
//   r  = max - min                      (group min/max, exact)
//   s  = clip(r * RN(1/15), 1e-5, 1e4)  [divide-by-broadcast-const ->
//                                        multiply by folded reciprocal]
//   zp = clip(-min / s, -1e4, 1e4)      [true IEEE f32 divide]
//   rzp= RNE(zp)
//   q  = RNE(x * RN(1/s))               [divide-by-broadcast [G,1] ->
//                                        mul by reciprocal (true divide)]
//   out= (clamp(q+rzp,0,15) - rzp) * s
//
// PERF LOG: R8 grid-stride 4B elems/lane: 113.3us (4.74 TB/s). R9 8 elems/
// lane + nontemporal: 117.6us — NT store bypasses L2 write-combining (fills
// hit 7 TB/s THROUGH L2), and intra-loop MLP didn't help (loop-carried
// serial chain not pipelined by compiler).
// R10: ONE-SHOT kernel, no loop. 16 consecutive floats per thread (4x
// float4), grid covers tensor exactly. Straight-line code -> all 4 loads
// issued before first use (4x MLP/wave), group = 8 lanes -> 3-step
// butterfly (6 ds ops, was 10), no loop-carried dependency; wave retires
// after stores so fresh waves keep the memory system saturated.

using f32x4 = __attribute__((ext_vector_type(4))) float;

__global__ __launch_bounds__(256) void fakequant_oneshot(
    const f32x4* __restrict__ x, f32x4* __restrict__ out)
{
    const float C15 = 1.0f / 15.0f;   // RN(1/15), constant-folded

    const int t = blockIdx.x * 256 + threadIdx.x;
    const int v = t * 4;              // this lane's four float4 slots

    f32x4 a = x[v];
    f32x4 b = x[v + 1];
    f32x4 c = x[v + 2];
    f32x4 e = x[v + 3];

    // local min/max over this lane's 16 consecutive elems (exact)
    float mn0 = fminf(fminf(a[0], a[1]), fminf(a[2], a[3]));
    float mn1 = fminf(fminf(b[0], b[1]), fminf(b[2], b[3]));
    float mn2 = fminf(fminf(c[0], c[1]), fminf(c[2], c[3]));
    float mn3 = fminf(fminf(e[0], e[1]), fminf(e[2], e[3]));
    float mx0 = fmaxf(fmaxf(a[0], a[1]), fmaxf(a[2], a[3]));
    float mx1 = fmaxf(fmaxf(b[0], b[1]), fmaxf(b[2], b[3]));
    float mx2 = fmaxf(fmaxf(c[0], c[1]), fmaxf(c[2], c[3]));
    float mx3 = fmaxf(fmaxf(e[0], e[1]), fmaxf(e[2], e[3]));
    float mn = fminf(fminf(mn0, mn1), fminf(mn2, mn3));
    float mx = fmaxf(fmaxf(mx0, mx1), fmaxf(mx2, mx3));

    // group = 8 consecutive lanes (8 lanes x 16 elems = 128): 3-step butterfly
    #pragma unroll
    for (int off = 4; off > 0; off >>= 1) {
        mn = fminf(mn, __shfl_xor(mn, off, 8));
        mx = fmaxf(mx, __shfl_xor(mx, off, 8));
    }

    // ---- locked numerics chain ----
    float s = (mx - mn) * C15;
    s = fminf(fmaxf(s, 1e-5f), 1e4f);
    float zp = (-mn) / s;                  // true IEEE divide
    zp = fminf(fmaxf(zp, -1e4f), 1e4f);
    float rzp = rintf(zp);
    float rs = 1.0f / s;                   // true IEEE divide, once

    #pragma unroll
    for (int i = 0; i < 4; ++i) {
        a[i] = (fminf(fmaxf(rintf(a[i] * rs) + rzp, 0.0f), 15.0f) - rzp) * s;
        b[i] = (fminf(fmaxf(rintf(b[i] * rs) + rzp, 0.0f), 15.0f) - rzp) * s;
        c[i] = (fminf(fmaxf(rintf(c[i] * rs) + rzp, 0.0f), 15.0f) - rzp) * s;
        e[i] = (fminf(fmaxf(rintf(e[i] * rs) + rzp, 0.0f), 15.0f) - rzp) * s;
    }

    out[v]     = a;
    out[v + 1] = b;
    out[v + 2] = c;
    out[v + 3] = e;
}

extern "C" void kernel_launch(void* const* d_in, const int* in_sizes, int n_in,
                              void* d_out, int out_size, void* d_ws, size_t ws_size,
                              hipStream_t stream)
{
    const float* x = (const float*)d_in[0];
    float* o = (float*)d_out;

    // n = 67108864 = 16384 blocks * 256 threads * 16 floats, exact cover.
    const int block = 256;
    const int grid = 16384;

    fakequant_oneshot<<<grid, block, 0, stream>>>(
        (const f32x4*)x, (f32x4*)o);
}